// Round 9
// baseline (178.249 us; speedup 1.0000x reference)
//
#include <hip/hip_runtime.h>
#include <hip/hip_bf16.h>

// GegenbauerKAN layer == fused BF16-MFMA GEMM, M=16384 N=512 K=4096 (i*8+d).
// ALPHA=1 => Chebyshev-U recurrence: C_{n+1} = 2t*C_n - C_{n-1}, t = tanh(x).
// R2: coeffs pre-converted to bf16 in d_ws (cvt_w).
// R3 (REVERTED): explicit dbuf -6%. R4: 4 blk/CU + cvt_pk (100us).
// R5: K-split waves (94us). R6: BN=256 flat. R7 (REVERTED): reg-direct,
//     1 wave/SIMD, latency-bound 144us. R8: reg-features + direct-B +
//     K-split TLP (2 waves/SIMD) -> 81us. R9 (REVERTED): scalar x-gather
//     112us. R10: pipelined restage == R8 (81us) -> chain latency NOT the
//     limiter; MfmaUtil*dur ~= per-SIMD MFMA demand (33us @16x16 ceiling),
//     kernel fails to COMPRESS with only 2 waves/SIMD.
// R11: 4 waves/SIMD. Wave tile 64x128 -> 64x64 (acc 4x4 = 64 VGPR, total
//     <=128) + launch_bounds(256,4). Grid (M/128, N/64) = 1024 blocks =
//     4 blocks/CU = 16 waves/CU = 4 waves/SIMD. N-panels 4->8 doubles
//     feature redundancy (~+7us VALU device-wide) — accepted for 2x TLP.
//     Skeleton otherwise identical to R10 (pipelined x-restage, direct-B,
//     setprio, K-half epilogue reduce).

#define I_DIM 512
#define O_DIM 512
#define NDEG 8
#define KH_ITERS 32            // 32 i-octets per K-half wave
#define W_ELEMS (I_DIM * O_DIM * NDEG)   // 2,097,152

typedef __attribute__((ext_vector_type(8))) short s8v;    // MFMA A/B frag (8 bf16)
typedef __attribute__((ext_vector_type(4))) float f32x4;  // MFMA C/D frag
typedef unsigned short u16;

// HW packed f32->bf16 (RNE): D[15:0]=bf16(lo), D[31:16]=bf16(hi). 1 VALU op.
__device__ __forceinline__ unsigned cvt_pk_bf16(float lo, float hi) {
    unsigned r;
    asm("v_cvt_pk_bf16_f32 %0, %1, %2" : "=v"(r) : "v"(lo), "v"(hi));
    return r;
}

__device__ __forceinline__ float fast_tanh(float v) {
    float e = __expf(v + v);
    float r = __builtin_amdgcn_rcpf(e + 1.0f);
    return 1.0f - (r + r);
}

// Build the A-fragment (8 Chebyshev-U features of one x value) in registers.
__device__ __forceinline__ s8v feat_frag(float xv) {
    const float t  = fast_tanh(xv);
    const float t2 = t + t;
    const float c1 = t2;
    const float c2 = t2 * c1 - 1.0f;
    const float c3 = t2 * c2 - c1;
    const float c4 = t2 * c3 - c2;
    const float c5 = t2 * c4 - c3;
    const float c6 = t2 * c5 - c4;
    const float c7 = t2 * c6 - c5;
    union { s8v s; unsigned u[4]; } pk;
    pk.u[0] = cvt_pk_bf16(1.0f, c1);
    pk.u[1] = cvt_pk_bf16(c2, c3);
    pk.u[2] = cvt_pk_bf16(c4, c5);
    pk.u[3] = cvt_pk_bf16(c6, c7);
    return pk.s;
}

// ---- one-shot coeffs fp32 -> bf16 into workspace (re-run every call; ws is re-poisoned)
extern "C" __global__ __launch_bounds__(256)
void cvt_w(const float* __restrict__ cf, u16* __restrict__ wbf) {
    const size_t idx = ((size_t)blockIdx.x * 256 + threadIdx.x) * 4;
    const float4 v = *reinterpret_cast<const float4*>(cf + idx);
    unsigned* dst = reinterpret_cast<unsigned*>(wbf + idx);
    dst[0] = cvt_pk_bf16(v.x, v.y);
    dst[1] = cvt_pk_bf16(v.z, v.w);
}

template <bool PRECONV>
__global__ __launch_bounds__(256, 4)
void gegen_gemm(const float* __restrict__ x,
                const float* __restrict__ cf,
                const u16* __restrict__ wbf,
                float* __restrict__ out)
{
    // 16KB union: main loop = per-wave x slots [wave][buf(512 floats)][64][8];
    //             epilogue  = K-half reduce buffer [m4][16][64] per tm chunk.
    __shared__ float smem[4096];

    const int tid  = threadIdx.x;
    const int lane = tid & 63;
    const int wave = tid >> 6;             // 0..3
    const int m4   = wave & 1;             // M-slice (64 rows)
    const int kh   = wave >> 1;            // K-half
    const int fm   = lane & 15;
    const int fq   = lane >> 4;

    const int bm0 = blockIdx.x * 128 + m4 * 64;   // wave's M base
    const int bn0 = blockIdx.y * 64;              // block's N base (64 cols)
    const int kbase = kh * (KH_ITERS * 8);        // starting i for this K-half

    // x staging: lane owns row (bm0 + lane)
    const float* xrow = x + (size_t)(bm0 + lane) * I_DIM + kbase;
    float* xslot = &smem[wave * 1024];            // [buf(512)][lane*8]

    f32x4 acc[4][4];
#pragma unroll
    for (int a = 0; a < 4; ++a)
#pragma unroll
        for (int b = 0; b < 4; ++b)
            acc[a][b] = (f32x4){0.0f, 0.0f, 0.0f, 0.0f};

    // ---- prologue: stage iter 0's x into slot buf 0 ----
    {
        const float4 xa = *reinterpret_cast<const float4*>(xrow);
        const float4 xb = *reinterpret_cast<const float4*>(xrow + 4);
        *reinterpret_cast<f32x4*>(&xslot[lane * 8])     = (f32x4){xa.x, xa.y, xa.z, xa.w};
        *reinterpret_cast<f32x4*>(&xslot[lane * 8 + 4]) = (f32x4){xb.x, xb.y, xb.z, xb.w};
    }

    for (int it = 0; it < KH_ITERS; ++it) {
        const int g8   = kbase + it * 8;
        const int buf  = (it & 1) * 512;
        const int nbuf = buf ^ 512;

        // ---- B frags: direct from global (L2-resident W), 16B each ----
        s8v bfr0[4], bfr1[4];
        if (PRECONV) {
            const u16* wb0 = wbf + ((size_t)(g8 + fq) * O_DIM + bn0 + fm) * NDEG;
            const u16* wb1 = wb0 + (size_t)4 * O_DIM * NDEG;   // i += 4
#pragma unroll
            for (int tn = 0; tn < 4; ++tn)
                bfr0[tn] = *reinterpret_cast<const s8v*>(wb0 + tn * 16 * NDEG);
#pragma unroll
            for (int tn = 0; tn < 4; ++tn)
                bfr1[tn] = *reinterpret_cast<const s8v*>(wb1 + tn * 16 * NDEG);
        } else {
            const float* wb0 = cf + ((size_t)(g8 + fq) * O_DIM + bn0 + fm) * NDEG;
            const float* wb1 = wb0 + (size_t)4 * O_DIM * NDEG;
#pragma unroll
            for (int tn = 0; tn < 4; ++tn) {
                const float4 w0 = reinterpret_cast<const float4*>(wb0 + tn * 16 * NDEG)[0];
                const float4 w1 = reinterpret_cast<const float4*>(wb0 + tn * 16 * NDEG)[1];
                union { s8v s; unsigned u[4]; } pk;
                pk.u[0] = cvt_pk_bf16(w0.x, w0.y);
                pk.u[1] = cvt_pk_bf16(w0.z, w0.w);
                pk.u[2] = cvt_pk_bf16(w1.x, w1.y);
                pk.u[3] = cvt_pk_bf16(w1.z, w1.w);
                bfr0[tn] = pk.s;
            }
#pragma unroll
            for (int tn = 0; tn < 4; ++tn) {
                const float4 w0 = reinterpret_cast<const float4*>(wb1 + tn * 16 * NDEG)[0];
                const float4 w1 = reinterpret_cast<const float4*>(wb1 + tn * 16 * NDEG)[1];
                union { s8v s; unsigned u[4]; } pk;
                pk.u[0] = cvt_pk_bf16(w0.x, w0.y);
                pk.u[1] = cvt_pk_bf16(w0.z, w0.w);
                pk.u[2] = cvt_pk_bf16(w1.x, w1.y);
                pk.u[3] = cvt_pk_bf16(w1.z, w1.w);
                bfr1[tn] = pk.s;
            }
        }

        // ---- issue next iter's x load (lands during this iter's MFMA wall) ----
        float4 xa2, xb2;
        const bool more = (it + 1 < KH_ITERS);
        if (more) {
            xa2 = *reinterpret_cast<const float4*>(xrow + (it + 1) * 8);
            xb2 = *reinterpret_cast<const float4*>(xrow + (it + 1) * 8 + 4);
        }

        // ---- fence: prev iter's (or prologue's) ds_write completed long ago ----
        asm volatile("s_waitcnt lgkmcnt(0)" ::: "memory");

        // ---- kc=0: features + 16 MFMAs ----
        s8v afr[4];
#pragma unroll
        for (int tm = 0; tm < 4; ++tm)
            afr[tm] = feat_frag(xslot[buf + (tm * 16 + fm) * 8 + fq]);

        __builtin_amdgcn_s_setprio(1);
#pragma unroll
        for (int tm = 0; tm < 4; ++tm)
#pragma unroll
            for (int tn = 0; tn < 4; ++tn)
                acc[tm][tn] = __builtin_amdgcn_mfma_f32_16x16x32_bf16(
                    afr[tm], bfr0[tn], acc[tm][tn], 0, 0, 0);
        __builtin_amdgcn_s_setprio(0);

        // ---- kc=1: features + 16 MFMAs ----
#pragma unroll
        for (int tm = 0; tm < 4; ++tm)
            afr[tm] = feat_frag(xslot[buf + (tm * 16 + fm) * 8 + 4 + fq]);

        __builtin_amdgcn_s_setprio(1);
#pragma unroll
        for (int tm = 0; tm < 4; ++tm)
#pragma unroll
            for (int tn = 0; tn < 4; ++tn)
                acc[tm][tn] = __builtin_amdgcn_mfma_f32_16x16x32_bf16(
                    afr[tm], bfr1[tn], acc[tm][tn], 0, 0, 0);
        __builtin_amdgcn_s_setprio(0);

        // ---- write-ahead: stage x[it+1] into the other slot ----
        if (more) {
            *reinterpret_cast<f32x4*>(&xslot[nbuf + lane * 8])     = (f32x4){xa2.x, xa2.y, xa2.z, xa2.w};
            *reinterpret_cast<f32x4*>(&xslot[nbuf + lane * 8 + 4]) = (f32x4){xb2.x, xb2.y, xb2.z, xb2.w};
        }
    }

    // ---- epilogue: K-half pair-reduction via LDS, chunked by tm ----
    // C/D frag: col=fm, row=fq*4+r within 16x16 tile (tm*16, tn*16).
    __syncthreads();   // x slots done block-wide; smem becomes reduce buffer
#pragma unroll
    for (int tm = 0; tm < 4; ++tm) {
        if (kh == 1) {
#pragma unroll
            for (int tn = 0; tn < 4; ++tn)
#pragma unroll
                for (int r = 0; r < 4; ++r)
                    smem[m4 * 1024 + (fq * 4 + r) * 64 + tn * 16 + fm] = acc[tm][tn][r];
        }
        __syncthreads();
        if (kh == 0) {
#pragma unroll
            for (int tn = 0; tn < 4; ++tn) {
                const int row = bm0 + tm * 16 + fq * 4;
                const int col = bn0 + tn * 16 + fm;
#pragma unroll
                for (int r = 0; r < 4; ++r)
                    out[(size_t)(row + r) * O_DIM + col] =
                        acc[tm][tn][r] + smem[m4 * 1024 + (fq * 4 + r) * 64 + tn * 16 + fm];
            }
        }
        __syncthreads();   // smem reused next tm chunk
    }
}

extern "C" void kernel_launch(void* const* d_in, const int* in_sizes, int n_in,
                              void* d_out, int out_size, void* d_ws, size_t ws_size,
                              hipStream_t stream) {
    const float* x  = (const float*)d_in[0];
    const float* cf = (const float*)d_in[1];
    float* out = (float*)d_out;
    const int M = in_sizes[0] / I_DIM;            // 16384
    dim3 grid(M / 128, O_DIM / 64);               // (128, 8) = 1024 blocks = 4/CU
    dim3 block(256, 1, 1);

    if (ws_size >= (size_t)W_ELEMS * sizeof(u16)) {
        u16* wbf = (u16*)d_ws;
        cvt_w<<<W_ELEMS / 1024, 256, 0, stream>>>(cf, wbf);
        gegen_gemm<true><<<grid, block, 0, stream>>>(x, cf, wbf, out);
    } else {
        gegen_gemm<false><<<grid, block, 0, stream>>>(x, cf, nullptr, out);
    }
}

// Round 10
// 158.365 us; speedup vs baseline: 1.1256x; 1.1256x over previous
//
#include <hip/hip_runtime.h>
#include <hip/hip_bf16.h>

// GegenbauerKAN layer == fused BF16-MFMA GEMM, M=16384 N=512 K=4096 (i*8+d).
// ALPHA=1 => Chebyshev-U recurrence: C_{n+1} = 2t*C_n - C_{n-1}, t = tanh(x).
// R2: coeffs pre-converted to bf16 in d_ws (cvt_w).
// R3 (REVERTED): explicit dbuf -6%. R4: 4 blk/CU + cvt_pk (100us).
// R5: K-split waves (94us). R6: BN=256 flat. R7 (REVERTED): 1 wave/SIMD,
//     144us. R8: reg-features + direct-B + K-split TLP -> 81us.
// R9 (REVERTED): scalar x-gather 112us. R10: pipelined restage == 81us.
// R11 (REVERTED): 64x64 tiles/4 waves-SIMD -> feature redundancy x2,
//     VALU 43%, 107us. Tile shrink is the wrong way to buy TLP.
// R12: back to R10 geometry (64x128 wave tile, panels=4, 2 waves/SIMD,
//     K-split kh + epilogue reduce), two changes:
//     (a) 16x16x32 -> 32x32x16 MFMA: +20% pipe rate (2495 vs 2075 TF
//         measured), half the issue slots, deeper pipe -> same-wave VALU
//         can hide in the MFMA shadow. A-frag = 8 features of one x
//         (row=l&31, i_local=l>>5); B-frag = 16 contiguous bytes of wbf.
//     (b) feature/MFMA software rotation: ks+1's feat_frags are computed
//         between ks's MFMA cluster issues (independent chains).
//     Plus: x-slot row stride padded to 10 floats (bank-conflict-free).

#define I_DIM 512
#define O_DIM 512
#define NDEG 8
#define KH_ITERS 32            // 32 i-octets per K-half wave
#define W_ELEMS (I_DIM * O_DIM * NDEG)   // 2,097,152

typedef __attribute__((ext_vector_type(8))) short s8v;     // MFMA A/B frag (8 bf16)
typedef __attribute__((ext_vector_type(16))) float f32x16; // 32x32 MFMA C/D frag
typedef unsigned short u16;

// HW packed f32->bf16 (RNE): D[15:0]=bf16(lo), D[31:16]=bf16(hi). 1 VALU op.
__device__ __forceinline__ unsigned cvt_pk_bf16(float lo, float hi) {
    unsigned r;
    asm("v_cvt_pk_bf16_f32 %0, %1, %2" : "=v"(r) : "v"(lo), "v"(hi));
    return r;
}

__device__ __forceinline__ float fast_tanh(float v) {
    float e = __expf(v + v);
    float r = __builtin_amdgcn_rcpf(e + 1.0f);
    return 1.0f - (r + r);
}

// Build the A-fragment (8 Chebyshev-U features of one x value) in registers.
__device__ __forceinline__ s8v feat_frag(float xv) {
    const float t  = fast_tanh(xv);
    const float t2 = t + t;
    const float c1 = t2;
    const float c2 = t2 * c1 - 1.0f;
    const float c3 = t2 * c2 - c1;
    const float c4 = t2 * c3 - c2;
    const float c5 = t2 * c4 - c3;
    const float c6 = t2 * c5 - c4;
    const float c7 = t2 * c6 - c5;
    union { s8v s; unsigned u[4]; } pk;
    pk.u[0] = cvt_pk_bf16(1.0f, c1);
    pk.u[1] = cvt_pk_bf16(c2, c3);
    pk.u[2] = cvt_pk_bf16(c4, c5);
    pk.u[3] = cvt_pk_bf16(c6, c7);
    return pk.s;
}

// ---- one-shot coeffs fp32 -> bf16 into workspace (re-run every call; ws is re-poisoned)
extern "C" __global__ __launch_bounds__(256)
void cvt_w(const float* __restrict__ cf, u16* __restrict__ wbf) {
    const size_t idx = ((size_t)blockIdx.x * 256 + threadIdx.x) * 4;
    const float4 v = *reinterpret_cast<const float4*>(cf + idx);
    unsigned* dst = reinterpret_cast<unsigned*>(wbf + idx);
    dst[0] = cvt_pk_bf16(v.x, v.y);
    dst[1] = cvt_pk_bf16(v.z, v.w);
}

// load one B frag (bf16 path) -- 16 contiguous bf16 of W at (i, col), d=0..7
__device__ __forceinline__ s8v ldb(const u16* p) {
    return *reinterpret_cast<const s8v*>(p);
}
// build one B frag from fp32 coeffs (fallback)
__device__ __forceinline__ s8v ldb_cvt(const float* p) {
    const float4 w0 = reinterpret_cast<const float4*>(p)[0];
    const float4 w1 = reinterpret_cast<const float4*>(p)[1];
    union { s8v s; unsigned u[4]; } pk;
    pk.u[0] = cvt_pk_bf16(w0.x, w0.y);
    pk.u[1] = cvt_pk_bf16(w0.z, w0.w);
    pk.u[2] = cvt_pk_bf16(w1.x, w1.y);
    pk.u[3] = cvt_pk_bf16(w1.z, w1.w);
    return pk.s;
}

template <bool PRECONV>
__global__ __launch_bounds__(256, 2)
void gegen_gemm(const float* __restrict__ x,
                const float* __restrict__ cf,
                const u16* __restrict__ wbf,
                float* __restrict__ out)
{
    // main loop: per-wave x slots [wave][buf][64 rows][10] (stride-10 pad,
    //            bank-conflict-free); epilogue: K-half reduce [m4][32][32].
    __shared__ float smem[5120];   // 20 KB

    const int tid  = threadIdx.x;
    const int lane = tid & 63;
    const int wave = tid >> 6;             // 0..3
    const int m4   = wave & 1;             // M-slice (64 rows)
    const int kh   = wave >> 1;            // K-half
    const int l31  = lane & 31;
    const int l5   = lane >> 5;            // 0/1

    const int bm0 = blockIdx.x * 128 + m4 * 64;   // wave's M base
    const int bn0 = blockIdx.y * 128;             // block's N base
    const int kbase = kh * (KH_ITERS * 8);        // starting i for this K-half

    // x staging: lane owns row (bm0 + lane)
    const float* xrow = x + (size_t)(bm0 + lane) * I_DIM + kbase;
    float* xslot = &smem[wave * 1280];            // [buf(640)][row*10 + e]

    f32x16 acc[2][4];
#pragma unroll
    for (int a = 0; a < 2; ++a)
#pragma unroll
        for (int b = 0; b < 4; ++b)
#pragma unroll
            for (int r = 0; r < 16; ++r)
                acc[a][b][r] = 0.0f;

    // ---- prologue: stage iter 0's x into slot buf 0 (stride-10 rows) ----
    {
        const float4 xa = *reinterpret_cast<const float4*>(xrow);
        const float4 xb = *reinterpret_cast<const float4*>(xrow + 4);
        float* p = &xslot[lane * 10];
        *reinterpret_cast<float2*>(p + 0) = make_float2(xa.x, xa.y);
        *reinterpret_cast<float2*>(p + 2) = make_float2(xa.z, xa.w);
        *reinterpret_cast<float2*>(p + 4) = make_float2(xb.x, xb.y);
        *reinterpret_cast<float2*>(p + 6) = make_float2(xb.z, xb.w);
    }

    for (int it = 0; it < KH_ITERS; ++it) {
        const int g8   = kbase + it * 8;
        const int buf  = (it & 1) * 640;
        const int nbuf = buf ^ 640;

        // ---- B frags: direct from global (L2-resident W) ----
        // lane l: i = g8 + ks*2 + (l>>5), col = bn0 + tn*32 + (l&31)
        s8v bfr[4][4];
        if (PRECONV) {
            const u16* wb = wbf + ((size_t)(g8 + l5) * O_DIM + bn0 + l31) * NDEG;
#pragma unroll
            for (int ks = 0; ks < 4; ++ks)
#pragma unroll
                for (int tn = 0; tn < 4; ++tn)
                    bfr[ks][tn] = ldb(wb + ((size_t)ks * 2 * O_DIM + tn * 32) * NDEG);
        } else {
            const float* wb = cf + ((size_t)(g8 + l5) * O_DIM + bn0 + l31) * NDEG;
#pragma unroll
            for (int ks = 0; ks < 4; ++ks)
#pragma unroll
                for (int tn = 0; tn < 4; ++tn)
                    bfr[ks][tn] = ldb_cvt(wb + ((size_t)ks * 2 * O_DIM + tn * 32) * NDEG);
        }

        // ---- issue next iter's x load (lands during this iter's MFMA walls) ----
        float4 xa2, xb2;
        const bool more = (it + 1 < KH_ITERS);
        if (more) {
            xa2 = *reinterpret_cast<const float4*>(xrow + (it + 1) * 8);
            xb2 = *reinterpret_cast<const float4*>(xrow + (it + 1) * 8 + 4);
        }

        // ---- fence: prev iter's ds_write (issued ~a full iter ago) ----
        asm volatile("s_waitcnt lgkmcnt(0)" ::: "memory");

        // per-lane x-slot read bases: rows (tm*32 + l31), elem (ks*2 + l5)
        const int bt0 = buf + l31 * 10 + l5;
        const int bt1 = buf + (32 + l31) * 10 + l5;

        // ---- rotated feature/MFMA pipeline over 4 k-steps ----
        s8v aA = feat_frag(xslot[bt0]);
        s8v aB = feat_frag(xslot[bt1]);
        s8v nA, nB;

        // ks = 0 (next feats interleave into MFMA shadow)
        nA = feat_frag(xslot[bt0 + 2]);
        nB = feat_frag(xslot[bt1 + 2]);
        __builtin_amdgcn_s_setprio(1);
#pragma unroll
        for (int tn = 0; tn < 4; ++tn)
            acc[0][tn] = __builtin_amdgcn_mfma_f32_32x32x16_bf16(aA, bfr[0][tn], acc[0][tn], 0, 0, 0);
#pragma unroll
        for (int tn = 0; tn < 4; ++tn)
            acc[1][tn] = __builtin_amdgcn_mfma_f32_32x32x16_bf16(aB, bfr[0][tn], acc[1][tn], 0, 0, 0);
        __builtin_amdgcn_s_setprio(0);
        aA = nA; aB = nB;

        // ks = 1
        nA = feat_frag(xslot[bt0 + 4]);
        nB = feat_frag(xslot[bt1 + 4]);
        __builtin_amdgcn_s_setprio(1);
#pragma unroll
        for (int tn = 0; tn < 4; ++tn)
            acc[0][tn] = __builtin_amdgcn_mfma_f32_32x32x16_bf16(aA, bfr[1][tn], acc[0][tn], 0, 0, 0);
#pragma unroll
        for (int tn = 0; tn < 4; ++tn)
            acc[1][tn] = __builtin_amdgcn_mfma_f32_32x32x16_bf16(aB, bfr[1][tn], acc[1][tn], 0, 0, 0);
        __builtin_amdgcn_s_setprio(0);
        aA = nA; aB = nB;

        // ks = 2
        nA = feat_frag(xslot[bt0 + 6]);
        nB = feat_frag(xslot[bt1 + 6]);
        __builtin_amdgcn_s_setprio(1);
#pragma unroll
        for (int tn = 0; tn < 4; ++tn)
            acc[0][tn] = __builtin_amdgcn_mfma_f32_32x32x16_bf16(aA, bfr[2][tn], acc[0][tn], 0, 0, 0);
#pragma unroll
        for (int tn = 0; tn < 4; ++tn)
            acc[1][tn] = __builtin_amdgcn_mfma_f32_32x32x16_bf16(aB, bfr[2][tn], acc[1][tn], 0, 0, 0);
        __builtin_amdgcn_s_setprio(0);
        aA = nA; aB = nB;

        // ks = 3: write-ahead restage (x loads landed), then last cluster
        if (more) {
            float* p = &xslot[nbuf + lane * 10];
            *reinterpret_cast<float2*>(p + 0) = make_float2(xa2.x, xa2.y);
            *reinterpret_cast<float2*>(p + 2) = make_float2(xa2.z, xa2.w);
            *reinterpret_cast<float2*>(p + 4) = make_float2(xb2.x, xb2.y);
            *reinterpret_cast<float2*>(p + 6) = make_float2(xb2.z, xb2.w);
        }
        __builtin_amdgcn_s_setprio(1);
#pragma unroll
        for (int tn = 0; tn < 4; ++tn)
            acc[0][tn] = __builtin_amdgcn_mfma_f32_32x32x16_bf16(aA, bfr[3][tn], acc[0][tn], 0, 0, 0);
#pragma unroll
        for (int tn = 0; tn < 4; ++tn)
            acc[1][tn] = __builtin_amdgcn_mfma_f32_32x32x16_bf16(aB, bfr[3][tn], acc[1][tn], 0, 0, 0);
        __builtin_amdgcn_s_setprio(0);
    }

    // ---- epilogue: K-half pair-reduction via LDS, chunked by (tm,tn) ----
    // 32x32 C/D: col=lane&31, row=(r&3)+8*(r>>2)+4*(lane>>5)  [m74/m101]
    __syncthreads();   // x slots done block-wide; smem becomes reduce buffer
#pragma unroll
    for (int tm = 0; tm < 2; ++tm) {
#pragma unroll
        for (int tn = 0; tn < 4; ++tn) {
            if (kh == 1) {
#pragma unroll
                for (int r = 0; r < 16; ++r) {
                    const int rowoff = (r & 3) + 8 * (r >> 2) + 4 * l5;
                    smem[m4 * 1024 + rowoff * 32 + l31] = acc[tm][tn][r];
                }
            }
            __syncthreads();
            if (kh == 0) {
#pragma unroll
                for (int r = 0; r < 16; ++r) {
                    const int rowoff = (r & 3) + 8 * (r >> 2) + 4 * l5;
                    const int row = bm0 + tm * 32 + rowoff;
                    const int col = bn0 + tn * 32 + l31;
                    out[(size_t)row * O_DIM + col] =
                        acc[tm][tn][r] + smem[m4 * 1024 + rowoff * 32 + l31];
                }
            }
            __syncthreads();   // smem reused next chunk
        }
    }
}

extern "C" void kernel_launch(void* const* d_in, const int* in_sizes, int n_in,
                              void* d_out, int out_size, void* d_ws, size_t ws_size,
                              hipStream_t stream) {
    const float* x  = (const float*)d_in[0];
    const float* cf = (const float*)d_in[1];
    float* out = (float*)d_out;
    const int M = in_sizes[0] / I_DIM;            // 16384
    dim3 grid(M / 128, O_DIM / 128);              // (128, 4) = 512 blocks = 2/CU
    dim3 block(256, 1, 1);

    if (ws_size >= (size_t)W_ELEMS * sizeof(u16)) {
        u16* wbf = (u16*)d_ws;
        cvt_w<<<W_ELEMS / 1024, 256, 0, stream>>>(cf, wbf);
        gegen_gemm<true><<<grid, block, 0, stream>>>(x, cf, wbf, out);
    } else {
        gegen_gemm<false><<<grid, block, 0, stream>>>(x, cf, nullptr, out);
    }
}

// Round 11
// 150.498 us; speedup vs baseline: 1.1844x; 1.0523x over previous
//
#include <hip/hip_runtime.h>
#include <hip/hip_bf16.h>

// GegenbauerKAN layer == fused BF16-MFMA GEMM, M=16384 N=512 K=4096 (i*8+d).
// ALPHA=1 => Chebyshev-U recurrence: C_{n+1} = 2t*C_n - C_{n-1}, t = tanh(x).
// R2: coeffs pre-converted to bf16 in d_ws (cvt_w).
// R3 (REVERTED): explicit dbuf -6%. R4: 4 blk/CU + cvt_pk (100us).
// R5: K-split waves (94us). R6: BN=256 flat. R7 (REVERTED): 1 wave/SIMD,
//     144us. R8: reg-features + direct-B + K-split TLP -> 81us.
// R9 (REVERTED): scalar x-gather 112us. R10: pipelined restage == 81us.
// R11 (REVERTED): small tiles -> VALU x2, 107us. R12: 32x32 shape, 88us.
//     R12 accounting: per-CU MFMA 29.6 + VALU 25 + B-L2 29 (W 4MB x M/64
//     rows = 1GB @ 34.5TB/s) = 84 ~= dur. THE THREE PIPES DON'T OVERLAP.
//     64x128 tile is the VALU/L2 optimum under regs; the gap is phase-lock:
//     2 waves/SIMD run identical code in lockstep (both in feat phase ->
//     MFMA idle; both in MFMA wall -> VALU idle), contention preserves it.
// R13: R10 + deliberate phase-skew: co-SIMD wave pairs are blocks (i,i+256);
//     second grid half sleeps ~1536cy (half a measured 3037cy wave-iter)
//     before the K-loop. Offset is self-sustaining (offset waves don't
//     contend -> equal iter times keep the stagger). K-order unchanged.
//     Plus: xslot stride 8->10 floats (conflict-free reads, R12-proven);
//     manual lgkmcnt fence dropped (compiler tracks private-slot deps).

#define I_DIM 512
#define O_DIM 512
#define NDEG 8
#define KH_ITERS 32            // 32 i-octets per K-half wave
#define W_ELEMS (I_DIM * O_DIM * NDEG)   // 2,097,152

typedef __attribute__((ext_vector_type(8))) short s8v;    // MFMA A/B frag (8 bf16)
typedef __attribute__((ext_vector_type(4))) float f32x4;  // MFMA C/D frag
typedef unsigned short u16;

// HW packed f32->bf16 (RNE): D[15:0]=bf16(lo), D[31:16]=bf16(hi). 1 VALU op.
__device__ __forceinline__ unsigned cvt_pk_bf16(float lo, float hi) {
    unsigned r;
    asm("v_cvt_pk_bf16_f32 %0, %1, %2" : "=v"(r) : "v"(lo), "v"(hi));
    return r;
}

__device__ __forceinline__ float fast_tanh(float v) {
    float e = __expf(v + v);
    float r = __builtin_amdgcn_rcpf(e + 1.0f);
    return 1.0f - (r + r);
}

// Build the A-fragment (8 Chebyshev-U features of one x value) in registers.
__device__ __forceinline__ s8v feat_frag(float xv) {
    const float t  = fast_tanh(xv);
    const float t2 = t + t;
    const float c1 = t2;
    const float c2 = t2 * c1 - 1.0f;
    const float c3 = t2 * c2 - c1;
    const float c4 = t2 * c3 - c2;
    const float c5 = t2 * c4 - c3;
    const float c6 = t2 * c5 - c4;
    const float c7 = t2 * c6 - c5;
    union { s8v s; unsigned u[4]; } pk;
    pk.u[0] = cvt_pk_bf16(1.0f, c1);
    pk.u[1] = cvt_pk_bf16(c2, c3);
    pk.u[2] = cvt_pk_bf16(c4, c5);
    pk.u[3] = cvt_pk_bf16(c6, c7);
    return pk.s;
}

// ---- one-shot coeffs fp32 -> bf16 into workspace (re-run every call; ws is re-poisoned)
extern "C" __global__ __launch_bounds__(256)
void cvt_w(const float* __restrict__ cf, u16* __restrict__ wbf) {
    const size_t idx = ((size_t)blockIdx.x * 256 + threadIdx.x) * 4;
    const float4 v = *reinterpret_cast<const float4*>(cf + idx);
    unsigned* dst = reinterpret_cast<unsigned*>(wbf + idx);
    dst[0] = cvt_pk_bf16(v.x, v.y);
    dst[1] = cvt_pk_bf16(v.z, v.w);
}

template <bool PRECONV>
__global__ __launch_bounds__(256, 2)
void gegen_gemm(const float* __restrict__ x,
                const float* __restrict__ cf,
                const u16* __restrict__ wbf,
                float* __restrict__ out)
{
    // main loop: per-wave x slots [wave][buf(640)][64 rows][10] (stride-10,
    // conflict-free reads); epilogue: K-half reduce [m4][16][128] (reused).
    __shared__ float smem[5120];   // 20 KB

    const int tid  = threadIdx.x;
    const int lane = tid & 63;
    const int wave = tid >> 6;             // 0..3
    const int m4   = wave & 1;             // M-slice (64 rows)
    const int kh   = wave >> 1;            // K-half
    const int fm   = lane & 15;
    const int fq   = lane >> 4;

    const int bm0 = blockIdx.x * 128 + m4 * 64;   // wave's M base
    const int bn0 = blockIdx.y * 128;             // block's N base
    const int kbase = kh * (KH_ITERS * 8);        // starting i for this K-half

    // ---- phase-skew: co-SIMD wave pairs come from blocks (i, i+256).
    // Offset the second dispatch wavefront by ~half a wave-iteration so the
    // pair interleaves feat-VALU with the partner's MFMA wall. One-time cost.
    const int linb = blockIdx.y * gridDim.x + blockIdx.x;   // 0..511
    if (linb >= 256) __builtin_amdgcn_s_sleep(24);          // ~1536 cyc

    // x staging: lane owns row (bm0 + lane)
    const float* xrow = x + (size_t)(bm0 + lane) * I_DIM + kbase;
    float* xslot = &smem[wave * 1280];            // [buf(640)][row*10 + e]

    f32x4 acc[4][8];
#pragma unroll
    for (int a = 0; a < 4; ++a)
#pragma unroll
        for (int b = 0; b < 8; ++b)
            acc[a][b] = (f32x4){0.0f, 0.0f, 0.0f, 0.0f};

    // ---- prologue: stage iter 0's x into slot buf 0 (stride-10 rows) ----
    {
        const float4 xa = *reinterpret_cast<const float4*>(xrow);
        const float4 xb = *reinterpret_cast<const float4*>(xrow + 4);
        float* p = &xslot[lane * 10];
        *reinterpret_cast<float2*>(p + 0) = make_float2(xa.x, xa.y);
        *reinterpret_cast<float2*>(p + 2) = make_float2(xa.z, xa.w);
        *reinterpret_cast<float2*>(p + 4) = make_float2(xb.x, xb.y);
        *reinterpret_cast<float2*>(p + 6) = make_float2(xb.z, xb.w);
    }

    for (int it = 0; it < KH_ITERS; ++it) {
        const int g8   = kbase + it * 8;
        const int buf  = (it & 1) * 640;
        const int nbuf = buf ^ 640;

        // ---- B frags: issue direct from global (L2-resident W), 16B each ----
        s8v bfr0[8], bfr1[8];
        if (PRECONV) {
            const u16* wb0 = wbf + ((size_t)(g8 + fq) * O_DIM + bn0 + fm) * NDEG;
            const u16* wb1 = wb0 + (size_t)4 * O_DIM * NDEG;   // i += 4
#pragma unroll
            for (int tn = 0; tn < 8; ++tn)
                bfr0[tn] = *reinterpret_cast<const s8v*>(wb0 + tn * 16 * NDEG);
#pragma unroll
            for (int tn = 0; tn < 8; ++tn)
                bfr1[tn] = *reinterpret_cast<const s8v*>(wb1 + tn * 16 * NDEG);
        } else {
            const float* wb0 = cf + ((size_t)(g8 + fq) * O_DIM + bn0 + fm) * NDEG;
            const float* wb1 = wb0 + (size_t)4 * O_DIM * NDEG;
#pragma unroll
            for (int tn = 0; tn < 8; ++tn) {
                const float4 w0 = reinterpret_cast<const float4*>(wb0 + tn * 16 * NDEG)[0];
                const float4 w1 = reinterpret_cast<const float4*>(wb0 + tn * 16 * NDEG)[1];
                union { s8v s; unsigned u[4]; } pk;
                pk.u[0] = cvt_pk_bf16(w0.x, w0.y);
                pk.u[1] = cvt_pk_bf16(w0.z, w0.w);
                pk.u[2] = cvt_pk_bf16(w1.x, w1.y);
                pk.u[3] = cvt_pk_bf16(w1.z, w1.w);
                bfr0[tn] = pk.s;
            }
#pragma unroll
            for (int tn = 0; tn < 8; ++tn) {
                const float4 w0 = reinterpret_cast<const float4*>(wb1 + tn * 16 * NDEG)[0];
                const float4 w1 = reinterpret_cast<const float4*>(wb1 + tn * 16 * NDEG)[1];
                union { s8v s; unsigned u[4]; } pk;
                pk.u[0] = cvt_pk_bf16(w0.x, w0.y);
                pk.u[1] = cvt_pk_bf16(w0.z, w0.w);
                pk.u[2] = cvt_pk_bf16(w1.x, w1.y);
                pk.u[3] = cvt_pk_bf16(w1.z, w1.w);
                bfr1[tn] = pk.s;
            }
        }

        // ---- issue next iter's x load (lands during this iter's MFMA wall) ----
        float4 xa2, xb2;
        const bool more = (it + 1 < KH_ITERS);
        if (more) {
            xa2 = *reinterpret_cast<const float4*>(xrow + (it + 1) * 8);
            xb2 = *reinterpret_cast<const float4*>(xrow + (it + 1) * 8 + 4);
        }

        // (no manual lgkmcnt: xslot is per-wave private; compiler inserts
        //  the needed waits for the ds_write -> ds_read dependency.)

        // ---- kc=0: features + 32 MFMAs ----
        s8v afr[4];
#pragma unroll
        for (int tm = 0; tm < 4; ++tm)
            afr[tm] = feat_frag(xslot[buf + (tm * 16 + fm) * 10 + fq]);

        __builtin_amdgcn_s_setprio(1);
#pragma unroll
        for (int tm = 0; tm < 4; ++tm)
#pragma unroll
            for (int tn = 0; tn < 8; ++tn)
                acc[tm][tn] = __builtin_amdgcn_mfma_f32_16x16x32_bf16(
                    afr[tm], bfr0[tn], acc[tm][tn], 0, 0, 0);
        __builtin_amdgcn_s_setprio(0);

        // ---- kc=1: features + 32 MFMAs ----
#pragma unroll
        for (int tm = 0; tm < 4; ++tm)
            afr[tm] = feat_frag(xslot[buf + (tm * 16 + fm) * 10 + 4 + fq]);

        __builtin_amdgcn_s_setprio(1);
#pragma unroll
        for (int tm = 0; tm < 4; ++tm)
#pragma unroll
            for (int tn = 0; tn < 8; ++tn)
                acc[tm][tn] = __builtin_amdgcn_mfma_f32_16x16x32_bf16(
                    afr[tm], bfr1[tn], acc[tm][tn], 0, 0, 0);
        __builtin_amdgcn_s_setprio(0);

        // ---- write-ahead: stage x[it+1] into the other slot ----
        if (more) {
            float* p = &xslot[nbuf + lane * 10];
            *reinterpret_cast<float2*>(p + 0) = make_float2(xa2.x, xa2.y);
            *reinterpret_cast<float2*>(p + 2) = make_float2(xa2.z, xa2.w);
            *reinterpret_cast<float2*>(p + 4) = make_float2(xb2.x, xb2.y);
            *reinterpret_cast<float2*>(p + 6) = make_float2(xb2.z, xb2.w);
        }
    }

    // ---- epilogue: K-half pair-reduction via LDS, chunked by tm ----
    // C/D frag: col=fm, row=fq*4+r within 16x16 tile (tm*16, tn*16).
    __syncthreads();   // x slots done block-wide; smem becomes reduce buffer
#pragma unroll
    for (int tm = 0; tm < 4; ++tm) {
        if (kh == 1) {
#pragma unroll
            for (int tn = 0; tn < 8; ++tn)
#pragma unroll
                for (int r = 0; r < 4; ++r)
                    smem[m4 * 2048 + (fq * 4 + r) * 128 + tn * 16 + fm] = acc[tm][tn][r];
        }
        __syncthreads();
        if (kh == 0) {
#pragma unroll
            for (int tn = 0; tn < 8; ++tn) {
                const int row = bm0 + tm * 16 + fq * 4;
                const int col = bn0 + tn * 16 + fm;
#pragma unroll
                for (int r = 0; r < 4; ++r)
                    out[(size_t)(row + r) * O_DIM + col] =
                        acc[tm][tn][r] + smem[m4 * 2048 + (fq * 4 + r) * 128 + tn * 16 + fm];
            }
        }
        __syncthreads();   // smem reused next tm chunk
    }
}

extern "C" void kernel_launch(void* const* d_in, const int* in_sizes, int n_in,
                              void* d_out, int out_size, void* d_ws, size_t ws_size,
                              hipStream_t stream) {
    const float* x  = (const float*)d_in[0];
    const float* cf = (const float*)d_in[1];
    float* out = (float*)d_out;
    const int M = in_sizes[0] / I_DIM;            // 16384
    dim3 grid(M / 128, O_DIM / 128);              // (128, 4) = 512 blocks = 2/CU
    dim3 block(256, 1, 1);

    if (ws_size >= (size_t)W_ELEMS * sizeof(u16)) {
        u16* wbf = (u16*)d_ws;
        cvt_w<<<W_ELEMS / 1024, 256, 0, stream>>>(cf, wbf);
        gegen_gemm<true><<<grid, block, 0, stream>>>(x, cf, wbf, out);
    } else {
        gegen_gemm<false><<<grid, block, 0, stream>>>(x, cf, nullptr, out);
    }
}